// Round 1
// baseline (2943.471 us; speedup 1.0000x reference)
//
#include <hip/hip_runtime.h>
#include <math.h>

#define Tn 4096
#define Dm 1024
#define Hn 8
#define DH 128

// ws float offsets
#define QO 0
#define KO ((size_t)Hn * Tn * DH)
#define VO (2 * (size_t)Hn * Tn * DH)
#define YHO (3 * (size_t)Hn * Tn * DH)

// ---------------------------------------------------------------------------
// Zero-fill (avoid hipMemsetAsync to be extra-safe under graph capture)
// ---------------------------------------------------------------------------
__global__ __launch_bounds__(256) void zero_kernel(float4* __restrict__ p) {
    size_t idx = (size_t)blockIdx.x * 256 + threadIdx.x;
    p[idx] = make_float4(0.f, 0.f, 0.f, 0.f);
}

// ---------------------------------------------------------------------------
// C[t][r] = sum_k A[t][k] * B[r][k];  A:[4096][1024], B:[1024][1024]
// mode 0: C[t*1024 + r]   (flat, used for final out-proj)
// mode 1: C[((r>>7)*Tn + t)*DH + (r&127)]   (per-head [H][T][dh] layout)
// 128x128 tile, BK=8, 8x8 per thread.
// ---------------------------------------------------------------------------
__global__ __launch_bounds__(256)
void gemm_nt(const float* __restrict__ A, const float* __restrict__ B,
             float* __restrict__ C, int mode) {
    __shared__ float As[8][132];
    __shared__ float Bs[8][132];
    int tid = threadIdx.x;
    int tx = tid & 15, ty = tid >> 4;
    int t0 = blockIdx.y * 128, r0 = blockIdx.x * 128;
    float acc[8][8] = {};
    int lr = tid >> 1;           // 0..127
    int lk = (tid & 1) * 4;      // 0 or 4
    const float* Ap = A + (size_t)(t0 + lr) * Dm + lk;
    const float* Bp = B + (size_t)(r0 + lr) * Dm + lk;
    for (int k0 = 0; k0 < Dm; k0 += 8) {
        float4 va = *(const float4*)(Ap + k0);
        float4 vb = *(const float4*)(Bp + k0);
        __syncthreads();
        As[lk + 0][lr] = va.x; As[lk + 1][lr] = va.y;
        As[lk + 2][lr] = va.z; As[lk + 3][lr] = va.w;
        Bs[lk + 0][lr] = vb.x; Bs[lk + 1][lr] = vb.y;
        Bs[lk + 2][lr] = vb.z; Bs[lk + 3][lr] = vb.w;
        __syncthreads();
#pragma unroll
        for (int k = 0; k < 8; ++k) {
            float a8[8], b8[8];
#pragma unroll
            for (int i = 0; i < 8; ++i) a8[i] = As[k][ty * 8 + i];
#pragma unroll
            for (int j = 0; j < 8; ++j) b8[j] = Bs[k][tx * 8 + j];
#pragma unroll
            for (int i = 0; i < 8; ++i)
#pragma unroll
                for (int j = 0; j < 8; ++j)
                    acc[i][j] = fmaf(a8[i], b8[j], acc[i][j]);
        }
    }
    if (mode == 0) {
#pragma unroll
        for (int i = 0; i < 8; ++i) {
            size_t ro = (size_t)(t0 + ty * 8 + i) * Dm + r0 + tx * 8;
#pragma unroll
            for (int j = 0; j < 8; ++j) C[ro + j] = acc[i][j];
        }
    } else {
        int r = r0 + tx * 8;
        int h = r >> 7;
        int e = r & 127;
#pragma unroll
        for (int i = 0; i < 8; ++i) {
            size_t ro = ((size_t)h * Tn + (t0 + ty * 8 + i)) * DH + e;
#pragma unroll
            for (int j = 0; j < 8; ++j) C[ro + j] = acc[i][j];
        }
    }
}

// ---------------------------------------------------------------------------
// S[t][s] = dot(Q[h][t][:], K[h][s][:]) + AP(t,s)
// AP(t,s): i = s>>1; w = 10000^(-i/512); s even -> sin(t*w), odd -> cos(t*w)
// 128x128 tile over (t,s), K-loop over dh=128 step 8.
// ---------------------------------------------------------------------------
__global__ __launch_bounds__(256)
void scores_kernel(const float* __restrict__ Q, const float* __restrict__ K,
                   float* __restrict__ S, int h) {
    __shared__ float As[8][132];   // As[k][t]
    __shared__ float Bs[8][132];   // Bs[k][s]
    __shared__ float wcol[128];
    const float* Qh = Q + (size_t)h * Tn * DH;
    const float* Kh = K + (size_t)h * Tn * DH;
    int tid = threadIdx.x;
    int tx = tid & 15, ty = tid >> 4;
    int s0 = blockIdx.x * 128, t0 = blockIdx.y * 128;
    if (tid < 128) {
        int s = s0 + tid;
        // log2(10000)/512 = 0.0259525632...
        wcol[tid] = exp2f(-(float)(s >> 1) * 0.0259525632f);
    }
    float acc[8][8] = {};
    int lr = tid >> 1;
    int lk = (tid & 1) * 4;
    const float* Qp = Qh + (size_t)(t0 + lr) * DH + lk;
    const float* Kp = Kh + (size_t)(s0 + lr) * DH + lk;
    for (int k0 = 0; k0 < DH; k0 += 8) {
        float4 va = *(const float4*)(Qp + k0);
        float4 vb = *(const float4*)(Kp + k0);
        __syncthreads();
        As[lk + 0][lr] = va.x; As[lk + 1][lr] = va.y;
        As[lk + 2][lr] = va.z; As[lk + 3][lr] = va.w;
        Bs[lk + 0][lr] = vb.x; Bs[lk + 1][lr] = vb.y;
        Bs[lk + 2][lr] = vb.z; Bs[lk + 3][lr] = vb.w;
        __syncthreads();
#pragma unroll
        for (int k = 0; k < 8; ++k) {
            float a8[8], b8[8];
#pragma unroll
            for (int i = 0; i < 8; ++i) a8[i] = As[k][ty * 8 + i];
#pragma unroll
            for (int j = 0; j < 8; ++j) b8[j] = Bs[k][tx * 8 + j];
#pragma unroll
            for (int i = 0; i < 8; ++i)
#pragma unroll
                for (int j = 0; j < 8; ++j)
                    acc[i][j] = fmaf(a8[i], b8[j], acc[i][j]);
        }
    }
    // add positional bias and store
#pragma unroll
    for (int i = 0; i < 8; ++i) {
        int t = t0 + ty * 8 + i;
        float tf = (float)t;
        size_t ro = (size_t)t * Tn + s0 + tx * 8;
#pragma unroll
        for (int jp = 0; jp < 4; ++jp) {
            float sv, cv;
            sincosf(tf * wcol[tx * 8 + 2 * jp], &sv, &cv);
            S[ro + 2 * jp]     = acc[i][2 * jp] + sv;
            S[ro + 2 * jp + 1] = acc[i][2 * jp + 1] + cv;
        }
    }
}

// ---------------------------------------------------------------------------
// In-place row softmax over S [4096][4096]; one block per row.
// ---------------------------------------------------------------------------
__global__ __launch_bounds__(256)
void softmax_kernel(float* __restrict__ S) {
    int t = blockIdx.x;
    float* row = S + (size_t)t * Tn;
    int tid = threadIdx.x;
    float v[16];
    float m = -1e30f;
#pragma unroll
    for (int i = 0; i < 16; ++i) {
        v[i] = row[i * 256 + tid];
        m = fmaxf(m, v[i]);
    }
    __shared__ float redm[4];
    __shared__ float reds[4];
#pragma unroll
    for (int off = 32; off > 0; off >>= 1) m = fmaxf(m, __shfl_down(m, off));
    if ((tid & 63) == 0) redm[tid >> 6] = m;
    __syncthreads();
    m = fmaxf(fmaxf(redm[0], redm[1]), fmaxf(redm[2], redm[3]));
    float sum = 0.f;
#pragma unroll
    for (int i = 0; i < 16; ++i) {
        v[i] = __expf(v[i] - m);
        sum += v[i];
    }
#pragma unroll
    for (int off = 32; off > 0; off >>= 1) sum += __shfl_down(sum, off);
    if ((tid & 63) == 0) reds[tid >> 6] = sum;
    __syncthreads();
    sum = reds[0] + reds[1] + reds[2] + reds[3];
    float inv = 1.0f / sum;
#pragma unroll
    for (int i = 0; i < 16; ++i) row[i * 256 + tid] = v[i] * inv;
}

// ---------------------------------------------------------------------------
// yh[t][h*128+e] += sum_{s in 512-chunk} S[t][s] * V[h][s][e]
// split-K over s (grid.x = 8 chunks), atomicAdd accumulation.
// ---------------------------------------------------------------------------
__global__ __launch_bounds__(256)
void av_kernel(const float* __restrict__ S, const float* __restrict__ V,
               float* __restrict__ yh, int h) {
    __shared__ float As[8][132];   // As[k][t]
    __shared__ float Bs[8][132];   // Bs[k][e]
    const float* Vh = V + (size_t)h * Tn * DH;
    int tid = threadIdx.x;
    int tx = tid & 15, ty = tid >> 4;
    int t0 = blockIdx.y * 128;
    int sbase = blockIdx.x * 512;
    float acc[8][8] = {};
    int lr = tid >> 1;
    int lk = (tid & 1) * 4;
    const float* Sp = S + (size_t)(t0 + lr) * Tn + sbase + lk;
    int vrow = tid >> 5;          // 0..7
    int vcol = (tid & 31) * 4;    // 0..124
    const float* Vp = Vh + (size_t)(sbase + vrow) * DH + vcol;
    for (int k0 = 0; k0 < 512; k0 += 8) {
        float4 va = *(const float4*)(Sp + k0);
        float4 vb = *(const float4*)(Vp + (size_t)k0 * DH);
        __syncthreads();
        As[lk + 0][lr] = va.x; As[lk + 1][lr] = va.y;
        As[lk + 2][lr] = va.z; As[lk + 3][lr] = va.w;
        Bs[vrow][vcol + 0] = vb.x; Bs[vrow][vcol + 1] = vb.y;
        Bs[vrow][vcol + 2] = vb.z; Bs[vrow][vcol + 3] = vb.w;
        __syncthreads();
#pragma unroll
        for (int k = 0; k < 8; ++k) {
            float a8[8], b8[8];
#pragma unroll
            for (int i = 0; i < 8; ++i) a8[i] = As[k][ty * 8 + i];
#pragma unroll
            for (int j = 0; j < 8; ++j) b8[j] = Bs[k][tx * 8 + j];
#pragma unroll
            for (int i = 0; i < 8; ++i)
#pragma unroll
                for (int j = 0; j < 8; ++j)
                    acc[i][j] = fmaf(a8[i], b8[j], acc[i][j]);
        }
    }
#pragma unroll
    for (int i = 0; i < 8; ++i) {
        size_t ro = (size_t)(t0 + ty * 8 + i) * Dm + h * DH + tx * 8;
#pragma unroll
        for (int j = 0; j < 8; ++j) atomicAdd(&yh[ro + j], acc[i][j]);
    }
}

// ---------------------------------------------------------------------------
extern "C" void kernel_launch(void* const* d_in, const int* in_sizes, int n_in,
                              void* d_out, int out_size, void* d_ws, size_t ws_size,
                              hipStream_t stream) {
    (void)in_sizes; (void)n_in; (void)out_size; (void)ws_size;
    const float* x    = (const float*)d_in[0];
    const float* Wq   = (const float*)d_in[1];
    const float* Wk   = (const float*)d_in[2];
    const float* Wv   = (const float*)d_in[3];
    const float* Wout = (const float*)d_in[4];

    float* out_y   = (float*)d_out;                       // [4096][1024]
    float* out_att = out_y + (size_t)Tn * Dm;             // [4096][4096]

    float* ws = (float*)d_ws;
    float* Q  = ws + QO;    // [H][T][DH]
    float* K  = ws + KO;
    float* V  = ws + VO;
    float* yh = ws + YHO;   // [T][H*DH]

    dim3 blk(256);

    // zero yh (atomic accumulation target): 4096*1024 floats = 1M float4
    zero_kernel<<<dim3((Tn * Dm / 4) / 256), blk, 0, stream>>>((float4*)yh);

    // QKV projections
    dim3 gp(Dm / 128, Tn / 128);   // (8, 32)
    gemm_nt<<<gp, blk, 0, stream>>>(x, Wq, Q, 1);
    gemm_nt<<<gp, blk, 0, stream>>>(x, Wk, K, 1);
    gemm_nt<<<gp, blk, 0, stream>>>(x, Wv, V, 1);

    // attention, head-serial; head 7 last so out_att ends as att[-1]
    for (int h = 0; h < Hn; ++h) {
        scores_kernel<<<dim3(Tn / 128, Tn / 128), blk, 0, stream>>>(Q, K, out_att, h);
        softmax_kernel<<<dim3(Tn), blk, 0, stream>>>(out_att);
        av_kernel<<<dim3(8, Tn / 128), blk, 0, stream>>>(out_att, V, yh, h);
    }

    // output projection
    gemm_nt<<<gp, blk, 0, stream>>>(yh, Wout, out_y, 0);
}

// Round 2
// 2060.023 us; speedup vs baseline: 1.4289x; 1.4289x over previous
//
#include <hip/hip_runtime.h>
#include <math.h>

#define Tn 4096
#define Dm 1024
#define Hn 8
#define DH 128

typedef __bf16 bf16x8 __attribute__((ext_vector_type(8)));
typedef float f32x4 __attribute__((ext_vector_type(4)));

#define LDS_STRIDE 40   // 32 + 8 pad (bf16 units): 80B row stride, ~2-way banks (free)

// ---------------------------------------------------------------------------
__global__ __launch_bounds__(256) void zero_kernel(float4* __restrict__ p) {
    size_t idx = (size_t)blockIdx.x * 256 + threadIdx.x;
    p[idx] = make_float4(0.f, 0.f, 0.f, 0.f);
}

// fp32 -> (hi, lo) bf16 split; n4 = n/4
__global__ __launch_bounds__(256)
void split_kernel(const float* __restrict__ in, __bf16* __restrict__ hi,
                  __bf16* __restrict__ lo, int n4) {
    int idx = blockIdx.x * 256 + threadIdx.x;
    if (idx >= n4) return;
    float4 v = ((const float4*)in)[idx];
    __attribute__((aligned(8))) __bf16 h[4], l[4];
    h[0] = (__bf16)v.x; h[1] = (__bf16)v.y; h[2] = (__bf16)v.z; h[3] = (__bf16)v.w;
    l[0] = (__bf16)(v.x - (float)h[0]);
    l[1] = (__bf16)(v.y - (float)h[1]);
    l[2] = (__bf16)(v.z - (float)h[2]);
    l[3] = (__bf16)(v.w - (float)h[3]);
    *(float2*)&hi[(size_t)idx * 4] = *(float2*)h;
    *(float2*)&lo[(size_t)idx * 4] = *(float2*)l;
}

// V[h][t][e] bf16 -> Vt[h][e][t] bf16, 64x64 LDS tiles
__global__ __launch_bounds__(256)
void vtrans_kernel(const __bf16* __restrict__ V, __bf16* __restrict__ Vt) {
    __shared__ __bf16 tile[64][80];
    int h = blockIdx.z, t0 = blockIdx.x * 64, e0 = blockIdx.y * 64;
    const __bf16* Vh = V + (size_t)h * Tn * DH;
    __bf16* Vth = Vt + (size_t)h * DH * Tn;
#pragma unroll
    for (int p = 0; p < 2; ++p) {
        int r = (threadIdx.x >> 3) + p * 32;   // t-local
        int c = (threadIdx.x & 7) * 8;         // e-local
        *(float4*)&tile[r][c] = *(const float4*)&Vh[(size_t)(t0 + r) * DH + e0 + c];
    }
    __syncthreads();
#pragma unroll
    for (int p = 0; p < 2; ++p) {
        int r = (threadIdx.x >> 3) + p * 32;   // e-local
        int c = (threadIdx.x & 7) * 8;         // t-local
        __attribute__((aligned(16))) __bf16 tmp[8];
#pragma unroll
        for (int j = 0; j < 8; ++j) tmp[j] = tile[c + j][r];
        *(float4*)&Vth[(size_t)(e0 + r) * Tn + t0 + c] = *(float4*)tmp;
    }
}

// ---------------------------------------------------------------------------
// Generic NT MFMA GEMM: C[m][n] = sum_k A[m][k]*B[n][k], bf16 inputs (optional
// hi/lo split => 3-pass), fp32 accumulate. 128x128 tile, 4 waves (2x2 of 64x64),
// 16x16x32 MFMA, BK=32.
// emode: 0 = fp32 store to C (ldC, coloff)
//        1 = split bf16 store to Ohi/Olo in [h][t][e] head layout (col -> h,e)
//        2 = bf16 store to Ohi, head layout
//        3 = fp32 store to C with sinusoidal positional bias added (scores)
//        4 = atomicAdd fp32 into C (ldC, coloff)  [split-K via gridDim.z]
// ---------------------------------------------------------------------------
__global__ __launch_bounds__(256)
void mfma_nt(const __bf16* __restrict__ Ahi, const __bf16* __restrict__ Alo,
             const __bf16* __restrict__ Bhi, const __bf16* __restrict__ Blo,
             int ldA, int ldB, int kbeg, int kchunk,
             float* __restrict__ C, int ldC, int coloff,
             __bf16* __restrict__ Ohi, __bf16* __restrict__ Olo,
             int emode) {
    __shared__ __bf16 smem[4][128 * LDS_STRIDE];
    const bool split = (Alo != nullptr);
    int tid = threadIdx.x;
    int m0 = blockIdx.y * 128, n0 = blockIdx.x * 128;
    int kb = kbeg + blockIdx.z * kchunk;
    int ke = kb + kchunk;
    int lane = tid & 63, wid = tid >> 6;
    int wm = (wid >> 1) * 64, wn = (wid & 1) * 64;
    int lm = lane & 15, q = lane >> 4;
    int sr = tid >> 2;            // staging row 0..63 (two passes)
    int sc = (tid & 3) * 8;       // staging col in bf16 units

    f32x4 acc[4][4];
#pragma unroll
    for (int i = 0; i < 4; ++i)
#pragma unroll
        for (int j = 0; j < 4; ++j) acc[i][j] = (f32x4){0.f, 0.f, 0.f, 0.f};

    for (int k0 = kb; k0 < ke; k0 += 32) {
        __syncthreads();
#pragma unroll
        for (int p = 0; p < 128; p += 64) {
            int r = sr + p;
            *(float4*)&smem[0][r * LDS_STRIDE + sc] =
                *(const float4*)&Ahi[(size_t)(m0 + r) * ldA + k0 + sc];
            *(float4*)&smem[2][r * LDS_STRIDE + sc] =
                *(const float4*)&Bhi[(size_t)(n0 + r) * ldB + k0 + sc];
            if (split) {
                *(float4*)&smem[1][r * LDS_STRIDE + sc] =
                    *(const float4*)&Alo[(size_t)(m0 + r) * ldA + k0 + sc];
                *(float4*)&smem[3][r * LDS_STRIDE + sc] =
                    *(const float4*)&Blo[(size_t)(n0 + r) * ldB + k0 + sc];
            }
        }
        __syncthreads();
        bf16x8 ah[4], bh[4], al[4], bl[4];
#pragma unroll
        for (int mt = 0; mt < 4; ++mt) {
            ah[mt] = *(const bf16x8*)&smem[0][(wm + mt * 16 + lm) * LDS_STRIDE + q * 8];
            if (split)
                al[mt] = *(const bf16x8*)&smem[1][(wm + mt * 16 + lm) * LDS_STRIDE + q * 8];
        }
#pragma unroll
        for (int nt = 0; nt < 4; ++nt) {
            bh[nt] = *(const bf16x8*)&smem[2][(wn + nt * 16 + lm) * LDS_STRIDE + q * 8];
            if (split)
                bl[nt] = *(const bf16x8*)&smem[3][(wn + nt * 16 + lm) * LDS_STRIDE + q * 8];
        }
#pragma unroll
        for (int mt = 0; mt < 4; ++mt)
#pragma unroll
            for (int nt = 0; nt < 4; ++nt) {
                acc[mt][nt] = __builtin_amdgcn_mfma_f32_16x16x32_bf16(ah[mt], bh[nt], acc[mt][nt], 0, 0, 0);
                if (split) {
                    acc[mt][nt] = __builtin_amdgcn_mfma_f32_16x16x32_bf16(ah[mt], bl[nt], acc[mt][nt], 0, 0, 0);
                    acc[mt][nt] = __builtin_amdgcn_mfma_f32_16x16x32_bf16(al[mt], bh[nt], acc[mt][nt], 0, 0, 0);
                }
            }
    }

    // epilogue. D layout: row = q*4 + r, col = lm (within each 16x16 tile)
    if (emode == 3) {
        float wv[4];
#pragma unroll
        for (int nt = 0; nt < 4; ++nt) {
            int s = n0 + wn + nt * 16 + lm;
            wv[nt] = exp2f(-(float)(s >> 1) * 0.025952563241f);  // 10000^(-(s>>1)/512)
        }
        int par = lm & 1;
#pragma unroll
        for (int mt = 0; mt < 4; ++mt)
#pragma unroll
            for (int r = 0; r < 4; ++r) {
                int t = m0 + wm + mt * 16 + q * 4 + r;
                float tf = (float)t;
#pragma unroll
                for (int nt = 0; nt < 4; ++nt) {
                    float sv, cv;
                    sincosf(tf * wv[nt], &sv, &cv);
                    float bias = par ? cv : sv;
                    C[(size_t)t * ldC + (n0 + wn + nt * 16 + lm)] = acc[mt][nt][r] + bias;
                }
            }
    } else if (emode == 0 || emode == 4) {
#pragma unroll
        for (int mt = 0; mt < 4; ++mt)
#pragma unroll
            for (int r = 0; r < 4; ++r) {
                int grow = m0 + wm + mt * 16 + q * 4 + r;
#pragma unroll
                for (int nt = 0; nt < 4; ++nt) {
                    int gc = n0 + wn + nt * 16 + lm;
                    if (emode == 0)
                        C[(size_t)grow * ldC + coloff + gc] = acc[mt][nt][r];
                    else
                        atomicAdd(&C[(size_t)grow * ldC + coloff + gc], acc[mt][nt][r]);
                }
            }
    } else {  // 1, 2: bf16 head-layout [h][t][e]
#pragma unroll
        for (int mt = 0; mt < 4; ++mt)
#pragma unroll
            for (int r = 0; r < 4; ++r) {
                int grow = m0 + wm + mt * 16 + q * 4 + r;
#pragma unroll
                for (int nt = 0; nt < 4; ++nt) {
                    int gc = n0 + wn + nt * 16 + lm;
                    int h = gc >> 7, e = gc & 127;
                    size_t o = ((size_t)h * Tn + grow) * DH + e;
                    float v = acc[mt][nt][r];
                    __bf16 hv = (__bf16)v;
                    Ohi[o] = hv;
                    if (emode == 1) Olo[o] = (__bf16)(v - (float)hv);
                }
            }
    }
}

// ---------------------------------------------------------------------------
// Row softmax over S [4096][4096] fp32; writes bf16 P always, fp32 back iff writef32.
// ---------------------------------------------------------------------------
__global__ __launch_bounds__(256)
void softmax_kernel(float* __restrict__ S, __bf16* __restrict__ P, int writef32) {
    int t = blockIdx.x;
    float* row = S + (size_t)t * Tn;
    __bf16* prow = P + (size_t)t * Tn;
    int tid = threadIdx.x;
    float v[16];
    float m = -1e30f;
#pragma unroll
    for (int i = 0; i < 16; ++i) {
        v[i] = row[i * 256 + tid];
        m = fmaxf(m, v[i]);
    }
    __shared__ float redm[4];
    __shared__ float reds[4];
#pragma unroll
    for (int off = 32; off > 0; off >>= 1) m = fmaxf(m, __shfl_down(m, off));
    if ((tid & 63) == 0) redm[tid >> 6] = m;
    __syncthreads();
    m = fmaxf(fmaxf(redm[0], redm[1]), fmaxf(redm[2], redm[3]));
    float sum = 0.f;
#pragma unroll
    for (int i = 0; i < 16; ++i) {
        v[i] = __expf(v[i] - m);
        sum += v[i];
    }
#pragma unroll
    for (int off = 32; off > 0; off >>= 1) sum += __shfl_down(sum, off);
    if ((tid & 63) == 0) reds[tid >> 6] = sum;
    __syncthreads();
    sum = reds[0] + reds[1] + reds[2] + reds[3];
    float inv = 1.0f / sum;
#pragma unroll
    for (int i = 0; i < 16; ++i) {
        float rres = v[i] * inv;
        if (writef32) row[i * 256 + tid] = rres;
        prow[i * 256 + tid] = (__bf16)rres;
    }
}

// ---------------------------------------------------------------------------
extern "C" void kernel_launch(void* const* d_in, const int* in_sizes, int n_in,
                              void* d_out, int out_size, void* d_ws, size_t ws_size,
                              hipStream_t stream) {
    (void)in_sizes; (void)n_in; (void)out_size; (void)ws_size;
    const float* x    = (const float*)d_in[0];
    const float* Wq   = (const float*)d_in[1];
    const float* Wk   = (const float*)d_in[2];
    const float* Wv   = (const float*)d_in[3];
    const float* Wout = (const float*)d_in[4];

    float* out_y   = (float*)d_out;              // [4096][1024]
    float* out_att = out_y + (size_t)Tn * Dm;    // [4096][4096]

    const size_t MB = 1ull << 20;
    char* W = (char*)d_ws;
    __bf16* xhi  = (__bf16*)(W + 0 * MB);    // 8MB
    __bf16* xlo  = (__bf16*)(W + 8 * MB);    // 8MB
    __bf16* Wqhi = (__bf16*)(W + 16 * MB);   // 2MB each
    __bf16* Wqlo = (__bf16*)(W + 18 * MB);
    __bf16* Wkhi = (__bf16*)(W + 20 * MB);
    __bf16* Wklo = (__bf16*)(W + 22 * MB);
    __bf16* Wvhi = (__bf16*)(W + 24 * MB);
    __bf16* Wvlo = (__bf16*)(W + 26 * MB);
    __bf16* Wohi = (__bf16*)(W + 28 * MB);
    __bf16* Wolo = (__bf16*)(W + 30 * MB);
    __bf16* Qhi  = (__bf16*)(W + 32 * MB);   // 8MB each, [H][T][DH]
    __bf16* Qlo  = (__bf16*)(W + 40 * MB);
    __bf16* Khi  = (__bf16*)(W + 48 * MB);
    __bf16* Klo  = (__bf16*)(W + 56 * MB);
    __bf16* Vb   = (__bf16*)(W + 64 * MB);   // 8MB [H][T][DH]
    __bf16* Vt   = (__bf16*)(W + 72 * MB);   // 8MB [H][DH][T]
    __bf16* Pb   = (__bf16*)(W + 80 * MB);   // 32MB [T][T]
    float*  yh   = (float*)(W + 112 * MB);   // 16MB [T][1024]
    __bf16* yhhi = (__bf16*)(W + 128 * MB);  // 8MB
    __bf16* yhlo = (__bf16*)(W + 136 * MB);  // 8MB  (total 144MB)

    dim3 blk(256);

    // splits
    split_kernel<<<dim3(Tn * Dm / 4 / 256), blk, 0, stream>>>(x, xhi, xlo, Tn * Dm / 4);
    split_kernel<<<dim3(Dm * Dm / 4 / 256), blk, 0, stream>>>(Wq, Wqhi, Wqlo, Dm * Dm / 4);
    split_kernel<<<dim3(Dm * Dm / 4 / 256), blk, 0, stream>>>(Wk, Wkhi, Wklo, Dm * Dm / 4);
    split_kernel<<<dim3(Dm * Dm / 4 / 256), blk, 0, stream>>>(Wv, Wvhi, Wvlo, Dm * Dm / 4);
    split_kernel<<<dim3(Dm * Dm / 4 / 256), blk, 0, stream>>>(Wout, Wohi, Wolo, Dm * Dm / 4);

    // QKV projections (split 3-pass MFMA)
    dim3 gp(Dm / 128, Tn / 128, 1);
    mfma_nt<<<gp, blk, 0, stream>>>(xhi, xlo, Wqhi, Wqlo, Dm, Dm, 0, Dm,
                                    nullptr, 0, 0, Qhi, Qlo, 1);
    mfma_nt<<<gp, blk, 0, stream>>>(xhi, xlo, Wkhi, Wklo, Dm, Dm, 0, Dm,
                                    nullptr, 0, 0, Khi, Klo, 1);
    mfma_nt<<<gp, blk, 0, stream>>>(xhi, xlo, Wvhi, Wvlo, Dm, Dm, 0, Dm,
                                    nullptr, 0, 0, Vb, nullptr, 2);
    vtrans_kernel<<<dim3(Tn / 64, DH / 64, Hn), blk, 0, stream>>>(Vb, Vt);
    zero_kernel<<<dim3(Tn * Dm / 4 / 256), blk, 0, stream>>>((float4*)yh);

    const size_t TD = (size_t)Tn * DH;
    for (int h = 0; h < Hn; ++h) {
        // S = Qh Kh^T + bias  (split 3-pass)
        mfma_nt<<<dim3(Tn / 128, Tn / 128, 1), blk, 0, stream>>>(
            Qhi + h * TD, Qlo + h * TD, Khi + h * TD, Klo + h * TD,
            DH, DH, 0, DH, out_att, Tn, 0, nullptr, nullptr, 3);
        softmax_kernel<<<dim3(Tn), blk, 0, stream>>>(out_att, Pb, h == 7 ? 1 : 0);
        // yh[:, h*128:(h+1)*128] += P @ Vh   (plain bf16, split-K=4, atomics)
        mfma_nt<<<dim3(1, Tn / 128, 4), blk, 0, stream>>>(
            Pb, nullptr, Vt + h * TD, nullptr,
            Tn, Tn, 0, Tn / 4, yh, Dm, h * DH, nullptr, nullptr, 4);
    }

    // output projection (split 3-pass)
    split_kernel<<<dim3(Tn * Dm / 4 / 256), blk, 0, stream>>>(yh, yhhi, yhlo, Tn * Dm / 4);
    mfma_nt<<<gp, blk, 0, stream>>>(yhhi, yhlo, Wohi, Wolo, Dm, Dm, 0, Dm,
                                    out_y, Dm, 0, nullptr, nullptr, 0);
}

// Round 3
// 1757.409 us; speedup vs baseline: 1.6749x; 1.1722x over previous
//
#include <hip/hip_runtime.h>
#include <math.h>

#define Tn 4096
#define Dm 1024
#define Hn 8
#define DH 128

typedef __bf16 bf16x8 __attribute__((ext_vector_type(8)));
typedef float f32x4 __attribute__((ext_vector_type(4)));

#define LDS_STRIDE 40   // 32 + 8 pad (bf16 units): 80B row stride, ~2-way banks (free)

// ---------------------------------------------------------------------------
// fp32 -> (hi, lo) bf16 split; n4 = n/4
__global__ __launch_bounds__(256)
void split_kernel(const float* __restrict__ in, __bf16* __restrict__ hi,
                  __bf16* __restrict__ lo, int n4) {
    int idx = blockIdx.x * 256 + threadIdx.x;
    if (idx >= n4) return;
    float4 v = ((const float4*)in)[idx];
    __attribute__((aligned(8))) __bf16 h[4], l[4];
    h[0] = (__bf16)v.x; h[1] = (__bf16)v.y; h[2] = (__bf16)v.z; h[3] = (__bf16)v.w;
    l[0] = (__bf16)(v.x - (float)h[0]);
    l[1] = (__bf16)(v.y - (float)h[1]);
    l[2] = (__bf16)(v.z - (float)h[2]);
    l[3] = (__bf16)(v.w - (float)h[3]);
    *(float2*)&hi[(size_t)idx * 4] = *(float2*)h;
    *(float2*)&lo[(size_t)idx * 4] = *(float2*)l;
}

// V[h][t][e] bf16 -> Vt[h][e][t] bf16, 64x64 LDS tiles
__global__ __launch_bounds__(256)
void vtrans_kernel(const __bf16* __restrict__ V, __bf16* __restrict__ Vt) {
    __shared__ __bf16 tile[64][80];
    int h = blockIdx.z, t0 = blockIdx.x * 64, e0 = blockIdx.y * 64;
    const __bf16* Vh = V + (size_t)h * Tn * DH;
    __bf16* Vth = Vt + (size_t)h * DH * Tn;
#pragma unroll
    for (int p = 0; p < 2; ++p) {
        int r = (threadIdx.x >> 3) + p * 32;   // t-local
        int c = (threadIdx.x & 7) * 8;         // e-local
        *(float4*)&tile[r][c] = *(const float4*)&Vh[(size_t)(t0 + r) * DH + e0 + c];
    }
    __syncthreads();
#pragma unroll
    for (int p = 0; p < 2; ++p) {
        int r = (threadIdx.x >> 3) + p * 32;   // e-local
        int c = (threadIdx.x & 7) * 8;         // t-local
        __attribute__((aligned(16))) __bf16 tmp[8];
#pragma unroll
        for (int j = 0; j < 8; ++j) tmp[j] = tile[c + j][r];
        *(float4*)&Vth[(size_t)(e0 + r) * Tn + t0 + c] = *(float4*)tmp;
    }
}

// ---------------------------------------------------------------------------
// Generic NT MFMA GEMM: C[m][n] = sum_k A[m][k]*B[n][k], bf16 inputs (optional
// hi/lo split => 3-pass), fp32 accumulate. 128x128 tile, 4 waves (2x2 of 64x64),
// 16x16x32 MFMA, BK=32.
// emode: 0 = fp32 store to C (ldC, coloff)
//        1 = split bf16 store to Ohi/Olo in [h][t][e] head layout (col -> h,e)
//        2 = bf16 store to Ohi, head layout
//        3 = fp32 store to C with sinusoidal positional bias added (scores)
//        5 = fp32 store of split-K partial: C + z*Tn*DH, [t][e] (n0==0, 128 cols)
// ---------------------------------------------------------------------------
__global__ __launch_bounds__(256)
void mfma_nt(const __bf16* __restrict__ Ahi, const __bf16* __restrict__ Alo,
             const __bf16* __restrict__ Bhi, const __bf16* __restrict__ Blo,
             int ldA, int ldB, int kbeg, int kchunk,
             float* __restrict__ C, int ldC, int coloff,
             __bf16* __restrict__ Ohi, __bf16* __restrict__ Olo,
             int emode) {
    __shared__ __bf16 smem[4][128 * LDS_STRIDE];
    const bool split = (Alo != nullptr);
    int tid = threadIdx.x;
    int m0 = blockIdx.y * 128, n0 = blockIdx.x * 128;
    int kb = kbeg + blockIdx.z * kchunk;
    int ke = kb + kchunk;
    int lane = tid & 63, wid = tid >> 6;
    int wm = (wid >> 1) * 64, wn = (wid & 1) * 64;
    int lm = lane & 15, q = lane >> 4;
    int sr = tid >> 2;            // staging row 0..63 (two passes)
    int sc = (tid & 3) * 8;       // staging col in bf16 units

    f32x4 acc[4][4];
#pragma unroll
    for (int i = 0; i < 4; ++i)
#pragma unroll
        for (int j = 0; j < 4; ++j) acc[i][j] = (f32x4){0.f, 0.f, 0.f, 0.f};

    for (int k0 = kb; k0 < ke; k0 += 32) {
        __syncthreads();
#pragma unroll
        for (int p = 0; p < 128; p += 64) {
            int r = sr + p;
            *(float4*)&smem[0][r * LDS_STRIDE + sc] =
                *(const float4*)&Ahi[(size_t)(m0 + r) * ldA + k0 + sc];
            *(float4*)&smem[2][r * LDS_STRIDE + sc] =
                *(const float4*)&Bhi[(size_t)(n0 + r) * ldB + k0 + sc];
            if (split) {
                *(float4*)&smem[1][r * LDS_STRIDE + sc] =
                    *(const float4*)&Alo[(size_t)(m0 + r) * ldA + k0 + sc];
                *(float4*)&smem[3][r * LDS_STRIDE + sc] =
                    *(const float4*)&Blo[(size_t)(n0 + r) * ldB + k0 + sc];
            }
        }
        __syncthreads();
        bf16x8 ah[4], bh[4], al[4], bl[4];
#pragma unroll
        for (int mt = 0; mt < 4; ++mt) {
            ah[mt] = *(const bf16x8*)&smem[0][(wm + mt * 16 + lm) * LDS_STRIDE + q * 8];
            if (split)
                al[mt] = *(const bf16x8*)&smem[1][(wm + mt * 16 + lm) * LDS_STRIDE + q * 8];
        }
#pragma unroll
        for (int nt = 0; nt < 4; ++nt) {
            bh[nt] = *(const bf16x8*)&smem[2][(wn + nt * 16 + lm) * LDS_STRIDE + q * 8];
            if (split)
                bl[nt] = *(const bf16x8*)&smem[3][(wn + nt * 16 + lm) * LDS_STRIDE + q * 8];
        }
#pragma unroll
        for (int mt = 0; mt < 4; ++mt)
#pragma unroll
            for (int nt = 0; nt < 4; ++nt) {
                acc[mt][nt] = __builtin_amdgcn_mfma_f32_16x16x32_bf16(ah[mt], bh[nt], acc[mt][nt], 0, 0, 0);
                if (split) {
                    acc[mt][nt] = __builtin_amdgcn_mfma_f32_16x16x32_bf16(ah[mt], bl[nt], acc[mt][nt], 0, 0, 0);
                    acc[mt][nt] = __builtin_amdgcn_mfma_f32_16x16x32_bf16(al[mt], bh[nt], acc[mt][nt], 0, 0, 0);
                }
            }
    }

    // epilogue. D layout: row = q*4 + r, col = lm (within each 16x16 tile)
    if (emode == 3) {
        float wv[4];
#pragma unroll
        for (int nt = 0; nt < 4; ++nt) {
            int s = n0 + wn + nt * 16 + lm;
            wv[nt] = exp2f(-(float)(s >> 1) * 0.025952563241f);  // 10000^(-(s>>1)/512)
        }
        int par = lm & 1;
#pragma unroll
        for (int mt = 0; mt < 4; ++mt)
#pragma unroll
            for (int r = 0; r < 4; ++r) {
                int t = m0 + wm + mt * 16 + q * 4 + r;
                float tf = (float)t;
#pragma unroll
                for (int nt = 0; nt < 4; ++nt) {
                    float sv, cv;
                    sincosf(tf * wv[nt], &sv, &cv);
                    float bias = par ? cv : sv;
                    C[(size_t)t * ldC + (n0 + wn + nt * 16 + lm)] = acc[mt][nt][r] + bias;
                }
            }
    } else if (emode == 0) {
#pragma unroll
        for (int mt = 0; mt < 4; ++mt)
#pragma unroll
            for (int r = 0; r < 4; ++r) {
                int grow = m0 + wm + mt * 16 + q * 4 + r;
#pragma unroll
                for (int nt = 0; nt < 4; ++nt) {
                    int gc = n0 + wn + nt * 16 + lm;
                    C[(size_t)grow * ldC + coloff + gc] = acc[mt][nt][r];
                }
            }
    } else if (emode == 5) {
        float* Cp = C + (size_t)blockIdx.z * Tn * DH;
#pragma unroll
        for (int mt = 0; mt < 4; ++mt)
#pragma unroll
            for (int r = 0; r < 4; ++r) {
                int grow = m0 + wm + mt * 16 + q * 4 + r;
#pragma unroll
                for (int nt = 0; nt < 4; ++nt) {
                    int gc = n0 + wn + nt * 16 + lm;   // 0..127
                    Cp[(size_t)grow * DH + gc] = acc[mt][nt][r];
                }
            }
    } else {  // 1, 2: bf16 head-layout [h][t][e]
#pragma unroll
        for (int mt = 0; mt < 4; ++mt)
#pragma unroll
            for (int r = 0; r < 4; ++r) {
                int grow = m0 + wm + mt * 16 + q * 4 + r;
#pragma unroll
                for (int nt = 0; nt < 4; ++nt) {
                    int gc = n0 + wn + nt * 16 + lm;
                    int h = gc >> 7, e = gc & 127;
                    size_t o = ((size_t)h * Tn + grow) * DH + e;
                    float v = acc[mt][nt][r];
                    __bf16 hv = (__bf16)v;
                    Ohi[o] = hv;
                    if (emode == 1) Olo[o] = (__bf16)(v - (float)hv);
                }
            }
    }
}

// ---------------------------------------------------------------------------
// Sum 8 split-K partials part[8][T][DH] into yh[:, h*DH : (h+1)*DH]
// ---------------------------------------------------------------------------
__global__ __launch_bounds__(256)
void reduce_kernel(const float* __restrict__ part, float* __restrict__ yh, int h) {
    int idx = blockIdx.x * 256 + threadIdx.x;   // 0 .. T*DH-1
    int t = idx >> 7, e = idx & 127;
    float s = 0.f;
#pragma unroll
    for (int z = 0; z < 8; ++z) s += part[(size_t)z * Tn * DH + idx];
    yh[(size_t)t * Dm + h * DH + e] = s;
}

// ---------------------------------------------------------------------------
// Row softmax over S [4096][4096] fp32; writes bf16 P always, fp32 back iff writef32.
// ---------------------------------------------------------------------------
__global__ __launch_bounds__(256)
void softmax_kernel(float* __restrict__ S, __bf16* __restrict__ P, int writef32) {
    int t = blockIdx.x;
    float* row = S + (size_t)t * Tn;
    __bf16* prow = P + (size_t)t * Tn;
    int tid = threadIdx.x;
    float v[16];
    float m = -1e30f;
#pragma unroll
    for (int i = 0; i < 16; ++i) {
        v[i] = row[i * 256 + tid];
        m = fmaxf(m, v[i]);
    }
    __shared__ float redm[4];
    __shared__ float reds[4];
#pragma unroll
    for (int off = 32; off > 0; off >>= 1) m = fmaxf(m, __shfl_down(m, off));
    if ((tid & 63) == 0) redm[tid >> 6] = m;
    __syncthreads();
    m = fmaxf(fmaxf(redm[0], redm[1]), fmaxf(redm[2], redm[3]));
    float sum = 0.f;
#pragma unroll
    for (int i = 0; i < 16; ++i) {
        v[i] = __expf(v[i] - m);
        sum += v[i];
    }
#pragma unroll
    for (int off = 32; off > 0; off >>= 1) sum += __shfl_down(sum, off);
    if ((tid & 63) == 0) reds[tid >> 6] = sum;
    __syncthreads();
    sum = reds[0] + reds[1] + reds[2] + reds[3];
    float inv = 1.0f / sum;
#pragma unroll
    for (int i = 0; i < 16; ++i) {
        float rres = v[i] * inv;
        if (writef32) row[i * 256 + tid] = rres;
        prow[i * 256 + tid] = (__bf16)rres;
    }
}

// ---------------------------------------------------------------------------
extern "C" void kernel_launch(void* const* d_in, const int* in_sizes, int n_in,
                              void* d_out, int out_size, void* d_ws, size_t ws_size,
                              hipStream_t stream) {
    (void)in_sizes; (void)n_in; (void)out_size; (void)ws_size;
    const float* x    = (const float*)d_in[0];
    const float* Wq   = (const float*)d_in[1];
    const float* Wk   = (const float*)d_in[2];
    const float* Wv   = (const float*)d_in[3];
    const float* Wout = (const float*)d_in[4];

    float* out_y   = (float*)d_out;              // [4096][1024]
    float* out_att = out_y + (size_t)Tn * Dm;    // [4096][4096]

    const size_t MB = 1ull << 20;
    char* W = (char*)d_ws;
    __bf16* xhi  = (__bf16*)(W + 0 * MB);    // 8MB
    __bf16* xlo  = (__bf16*)(W + 8 * MB);    // 8MB
    __bf16* Wqhi = (__bf16*)(W + 16 * MB);   // 2MB each
    __bf16* Wqlo = (__bf16*)(W + 18 * MB);
    __bf16* Wkhi = (__bf16*)(W + 20 * MB);
    __bf16* Wklo = (__bf16*)(W + 22 * MB);
    __bf16* Wvhi = (__bf16*)(W + 24 * MB);
    __bf16* Wvlo = (__bf16*)(W + 26 * MB);
    __bf16* Wohi = (__bf16*)(W + 28 * MB);
    __bf16* Wolo = (__bf16*)(W + 30 * MB);
    __bf16* Qhi  = (__bf16*)(W + 32 * MB);   // 8MB each, [H][T][DH]
    __bf16* Qlo  = (__bf16*)(W + 40 * MB);
    __bf16* Khi  = (__bf16*)(W + 48 * MB);
    __bf16* Klo  = (__bf16*)(W + 56 * MB);
    __bf16* Vb   = (__bf16*)(W + 64 * MB);   // 8MB [H][T][DH]
    __bf16* Vt   = (__bf16*)(W + 72 * MB);   // 8MB [H][DH][T]
    __bf16* Pb   = (__bf16*)(W + 80 * MB);   // 32MB [T][T]
    float*  yh   = (float*)(W + 112 * MB);   // 16MB [T][1024]
    // region 128..144MB is dual-use (time-disjoint):
    float*  part = (float*)(W + 128 * MB);   // 16MB [8][T][DH]  (head loop only)
    __bf16* yhhi = (__bf16*)(W + 128 * MB);  // 8MB  (after head loop)
    __bf16* yhlo = (__bf16*)(W + 136 * MB);  // 8MB  (total 144MB)

    dim3 blk(256);

    // splits
    split_kernel<<<dim3(Tn * Dm / 4 / 256), blk, 0, stream>>>(x, xhi, xlo, Tn * Dm / 4);
    split_kernel<<<dim3(Dm * Dm / 4 / 256), blk, 0, stream>>>(Wq, Wqhi, Wqlo, Dm * Dm / 4);
    split_kernel<<<dim3(Dm * Dm / 4 / 256), blk, 0, stream>>>(Wk, Wkhi, Wklo, Dm * Dm / 4);
    split_kernel<<<dim3(Dm * Dm / 4 / 256), blk, 0, stream>>>(Wv, Wvhi, Wvlo, Dm * Dm / 4);
    split_kernel<<<dim3(Dm * Dm / 4 / 256), blk, 0, stream>>>(Wout, Wohi, Wolo, Dm * Dm / 4);

    // QKV projections (split 3-pass MFMA)
    dim3 gp(Dm / 128, Tn / 128, 1);
    mfma_nt<<<gp, blk, 0, stream>>>(xhi, xlo, Wqhi, Wqlo, Dm, Dm, 0, Dm,
                                    nullptr, 0, 0, Qhi, Qlo, 1);
    mfma_nt<<<gp, blk, 0, stream>>>(xhi, xlo, Wkhi, Wklo, Dm, Dm, 0, Dm,
                                    nullptr, 0, 0, Khi, Klo, 1);
    mfma_nt<<<gp, blk, 0, stream>>>(xhi, xlo, Wvhi, Wvlo, Dm, Dm, 0, Dm,
                                    nullptr, 0, 0, Vb, nullptr, 2);
    vtrans_kernel<<<dim3(Tn / 64, DH / 64, Hn), blk, 0, stream>>>(Vb, Vt);

    const size_t TD = (size_t)Tn * DH;
    for (int h = 0; h < Hn; ++h) {
        // S = Qh Kh^T + bias  (split 3-pass)
        mfma_nt<<<dim3(Tn / 128, Tn / 128, 1), blk, 0, stream>>>(
            Qhi + h * TD, Qlo + h * TD, Khi + h * TD, Klo + h * TD,
            DH, DH, 0, DH, out_att, Tn, 0, nullptr, nullptr, 3);
        softmax_kernel<<<dim3(Tn), blk, 0, stream>>>(out_att, Pb, h == 7 ? 1 : 0);
        // part[z] = P[:, z*512:(z+1)*512] @ Vh[z*512:(z+1)*512, :]  (bf16, no atomics)
        mfma_nt<<<dim3(1, Tn / 128, 8), blk, 0, stream>>>(
            Pb, nullptr, Vt + h * TD, nullptr,
            Tn, Tn, 0, Tn / 8, part, 0, 0, nullptr, nullptr, 5);
        // yh[:, h*128:(h+1)*128] = sum_z part[z]
        reduce_kernel<<<dim3(Tn * DH / 256), blk, 0, stream>>>(part, yh, h);
    }

    // output projection (split 3-pass)
    split_kernel<<<dim3(Tn * Dm / 4 / 256), blk, 0, stream>>>(yh, yhhi, yhlo, Tn * Dm / 4);
    mfma_nt<<<gp, blk, 0, stream>>>(yhhi, yhlo, Wohi, Wolo, Dm, Dm, 0, Dm,
                                    out_y, Dm, 0, nullptr, nullptr, 0);
}

// Round 4
// 1108.994 us; speedup vs baseline: 2.6542x; 1.5847x over previous
//
#include <hip/hip_runtime.h>
#include <math.h>

#define Tn 4096
#define Dm 1024
#define Hn 8
#define DH 128

typedef __bf16 bf16x8 __attribute__((ext_vector_type(8)));
typedef float f32x4 __attribute__((ext_vector_type(4)));

#define LDS_STRIDE 40   // 32 + 8 pad (bf16 units)
#define LOG2E 1.4426950408889634f
#define WEXP 0.025952563241307518f  // log2(10000)/512

#define MFMA(a, b, c) __builtin_amdgcn_mfma_f32_16x16x32_bf16((a), (b), (c), 0, 0, 0)

// ---------------------------------------------------------------------------
// fp32 -> (hi, lo) bf16 split; n4 = n/4
__global__ __launch_bounds__(256)
void split_kernel(const float* __restrict__ in, __bf16* __restrict__ hi,
                  __bf16* __restrict__ lo, int n4) {
    int idx = blockIdx.x * 256 + threadIdx.x;
    if (idx >= n4) return;
    float4 v = ((const float4*)in)[idx];
    __attribute__((aligned(8))) __bf16 h[4], l[4];
    h[0] = (__bf16)v.x; h[1] = (__bf16)v.y; h[2] = (__bf16)v.z; h[3] = (__bf16)v.w;
    l[0] = (__bf16)(v.x - (float)h[0]);
    l[1] = (__bf16)(v.y - (float)h[1]);
    l[2] = (__bf16)(v.z - (float)h[2]);
    l[3] = (__bf16)(v.w - (float)h[3]);
    *(float2*)&hi[(size_t)idx * 4] = *(float2*)h;
    *(float2*)&lo[(size_t)idx * 4] = *(float2*)l;
}

// V[h][t][e] bf16 -> Vt[h][e][t] bf16, 64x64 LDS tiles
__global__ __launch_bounds__(256)
void vtrans_kernel(const __bf16* __restrict__ V, __bf16* __restrict__ Vt) {
    __shared__ __bf16 tile[64][80];
    int h = blockIdx.z, t0 = blockIdx.x * 64, e0 = blockIdx.y * 64;
    const __bf16* Vh = V + (size_t)h * Tn * DH;
    __bf16* Vth = Vt + (size_t)h * DH * Tn;
#pragma unroll
    for (int p = 0; p < 2; ++p) {
        int r = (threadIdx.x >> 3) + p * 32;
        int c = (threadIdx.x & 7) * 8;
        *(float4*)&tile[r][c] = *(const float4*)&Vh[(size_t)(t0 + r) * DH + e0 + c];
    }
    __syncthreads();
#pragma unroll
    for (int p = 0; p < 2; ++p) {
        int r = (threadIdx.x >> 3) + p * 32;
        int c = (threadIdx.x & 7) * 8;
        __attribute__((aligned(16))) __bf16 tmp[8];
#pragma unroll
        for (int j = 0; j < 8; ++j) tmp[j] = tile[c + j][r];
        *(float4*)&Vth[(size_t)(e0 + r) * Tn + t0 + c] = *(float4*)tmp;
    }
}

// ---------------------------------------------------------------------------
// Generic NT MFMA GEMM (used for projections + head-7 unfused path).
// emode: 0 fp32 store; 1 split bf16 head-layout; 2 bf16 head-layout;
//        3 fp32 + positional bias (scores); 5 split-K partial [z][t][e]
// ---------------------------------------------------------------------------
__global__ __launch_bounds__(256)
void mfma_nt(const __bf16* __restrict__ Ahi, const __bf16* __restrict__ Alo,
             const __bf16* __restrict__ Bhi, const __bf16* __restrict__ Blo,
             int ldA, int ldB, int kbeg, int kchunk,
             float* __restrict__ C, int ldC, int coloff,
             __bf16* __restrict__ Ohi, __bf16* __restrict__ Olo,
             int emode) {
    __shared__ __bf16 smem[4][128 * LDS_STRIDE];
    const bool split = (Alo != nullptr);
    int tid = threadIdx.x;
    int m0 = blockIdx.y * 128, n0 = blockIdx.x * 128;
    int kb = kbeg + blockIdx.z * kchunk;
    int ke = kb + kchunk;
    int lane = tid & 63, wid = tid >> 6;
    int wm = (wid >> 1) * 64, wn = (wid & 1) * 64;
    int lm = lane & 15, q = lane >> 4;
    int sr = tid >> 2;
    int sc = (tid & 3) * 8;

    f32x4 acc[4][4];
#pragma unroll
    for (int i = 0; i < 4; ++i)
#pragma unroll
        for (int j = 0; j < 4; ++j) acc[i][j] = (f32x4){0.f, 0.f, 0.f, 0.f};

    for (int k0 = kb; k0 < ke; k0 += 32) {
        __syncthreads();
#pragma unroll
        for (int p = 0; p < 128; p += 64) {
            int r = sr + p;
            *(float4*)&smem[0][r * LDS_STRIDE + sc] =
                *(const float4*)&Ahi[(size_t)(m0 + r) * ldA + k0 + sc];
            *(float4*)&smem[2][r * LDS_STRIDE + sc] =
                *(const float4*)&Bhi[(size_t)(n0 + r) * ldB + k0 + sc];
            if (split) {
                *(float4*)&smem[1][r * LDS_STRIDE + sc] =
                    *(const float4*)&Alo[(size_t)(m0 + r) * ldA + k0 + sc];
                *(float4*)&smem[3][r * LDS_STRIDE + sc] =
                    *(const float4*)&Blo[(size_t)(n0 + r) * ldB + k0 + sc];
            }
        }
        __syncthreads();
        bf16x8 ah[4], bh[4], al[4], bl[4];
#pragma unroll
        for (int mt = 0; mt < 4; ++mt) {
            ah[mt] = *(const bf16x8*)&smem[0][(wm + mt * 16 + lm) * LDS_STRIDE + q * 8];
            if (split)
                al[mt] = *(const bf16x8*)&smem[1][(wm + mt * 16 + lm) * LDS_STRIDE + q * 8];
        }
#pragma unroll
        for (int nt = 0; nt < 4; ++nt) {
            bh[nt] = *(const bf16x8*)&smem[2][(wn + nt * 16 + lm) * LDS_STRIDE + q * 8];
            if (split)
                bl[nt] = *(const bf16x8*)&smem[3][(wn + nt * 16 + lm) * LDS_STRIDE + q * 8];
        }
#pragma unroll
        for (int mt = 0; mt < 4; ++mt)
#pragma unroll
            for (int nt = 0; nt < 4; ++nt) {
                acc[mt][nt] = MFMA(ah[mt], bh[nt], acc[mt][nt]);
                if (split) {
                    acc[mt][nt] = MFMA(ah[mt], bl[nt], acc[mt][nt]);
                    acc[mt][nt] = MFMA(al[mt], bh[nt], acc[mt][nt]);
                }
            }
    }

    if (emode == 3) {
        float wv[4];
#pragma unroll
        for (int nt = 0; nt < 4; ++nt) {
            int s = n0 + wn + nt * 16 + lm;
            wv[nt] = exp2f(-(float)(s >> 1) * WEXP);
        }
        int par = lm & 1;
#pragma unroll
        for (int mt = 0; mt < 4; ++mt)
#pragma unroll
            for (int r = 0; r < 4; ++r) {
                int t = m0 + wm + mt * 16 + q * 4 + r;
                float tf = (float)t;
#pragma unroll
                for (int nt = 0; nt < 4; ++nt) {
                    float sv, cv;
                    sincosf(tf * wv[nt], &sv, &cv);
                    float bias = par ? cv : sv;
                    C[(size_t)t * ldC + (n0 + wn + nt * 16 + lm)] = acc[mt][nt][r] + bias;
                }
            }
    } else if (emode == 0) {
#pragma unroll
        for (int mt = 0; mt < 4; ++mt)
#pragma unroll
            for (int r = 0; r < 4; ++r) {
                int grow = m0 + wm + mt * 16 + q * 4 + r;
#pragma unroll
                for (int nt = 0; nt < 4; ++nt) {
                    int gc = n0 + wn + nt * 16 + lm;
                    C[(size_t)grow * ldC + coloff + gc] = acc[mt][nt][r];
                }
            }
    } else if (emode == 5) {
        float* Cp = C + (size_t)blockIdx.z * Tn * DH;
#pragma unroll
        for (int mt = 0; mt < 4; ++mt)
#pragma unroll
            for (int r = 0; r < 4; ++r) {
                int grow = m0 + wm + mt * 16 + q * 4 + r;
#pragma unroll
                for (int nt = 0; nt < 4; ++nt) {
                    int gc = n0 + wn + nt * 16 + lm;
                    Cp[(size_t)grow * DH + gc] = acc[mt][nt][r];
                }
            }
    } else {
#pragma unroll
        for (int mt = 0; mt < 4; ++mt)
#pragma unroll
            for (int r = 0; r < 4; ++r) {
                int grow = m0 + wm + mt * 16 + q * 4 + r;
#pragma unroll
                for (int nt = 0; nt < 4; ++nt) {
                    int gc = n0 + wn + nt * 16 + lm;
                    int h = gc >> 7, e = gc & 127;
                    size_t o = ((size_t)h * Tn + grow) * DH + e;
                    float v = acc[mt][nt][r];
                    __bf16 hv = (__bf16)v;
                    Ohi[o] = hv;
                    if (emode == 1) Olo[o] = (__bf16)(v - (float)hv);
                }
            }
    }
}

// ---------------------------------------------------------------------------
// Flash attention for heads 0..6: S never hits HBM.
// Block = 256 threads (4 waves), 128 Q-rows; each wave owns 32 rows x 128 cols.
// grid (32 q-tiles, 7 heads). K staged in 32-dh LDS chunks (hi/lo split,
// 3-pass MFMA); bias+online softmax in registers (row state in 16-lane
// groups, shfl_xor butterfly); P relayout via LDS; V B-frags direct from L2.
// ---------------------------------------------------------------------------
__global__ __launch_bounds__(256)
void flash_kernel(const __bf16* __restrict__ Qhi, const __bf16* __restrict__ Qlo,
                  const __bf16* __restrict__ Khi, const __bf16* __restrict__ Klo,
                  const __bf16* __restrict__ Vt, float* __restrict__ yh) {
    __shared__ __bf16 Ks[2][128][40];   // 20480 B: [hi/lo][s][32dh + 8 pad]
    __shared__ __bf16 Ps[128][132];     // 33792 B
    int h = blockIdx.y;
    int m0 = blockIdx.x * 128;
    const size_t TD = (size_t)Tn * DH;
    const __bf16* Qh = Qhi + h * TD;
    const __bf16* Ql = Qlo + h * TD;
    const __bf16* Kh = Khi + h * TD;
    const __bf16* Kl = Klo + h * TD;
    const __bf16* Vh = Vt + h * TD;

    int tid = threadIdx.x;
    int lane = tid & 63, wid = tid >> 6;
    int lm = lane & 15, q = lane >> 4;
    int wr0 = wid * 32;

    // Q fragments in registers (A-layout): rows m0+wr0+mt*16+lm, k = kc*32+q*8
    bf16x8 qfh[2][4], qfl[2][4];
#pragma unroll
    for (int mt = 0; mt < 2; ++mt)
#pragma unroll
        for (int kc = 0; kc < 4; ++kc) {
            size_t o = (size_t)(m0 + wr0 + mt * 16 + lm) * DH + kc * 32 + q * 8;
            qfh[mt][kc] = *(const bf16x8*)&Qh[o];
            qfl[mt][kc] = *(const bf16x8*)&Ql[o];
        }

    f32x4 accO[2][8];
#pragma unroll
    for (int mt = 0; mt < 2; ++mt)
#pragma unroll
        for (int nt = 0; nt < 8; ++nt) accO[mt][nt] = (f32x4){0.f, 0.f, 0.f, 0.f};
    float mrow[2][4], lrow[2][4];
#pragma unroll
    for (int mt = 0; mt < 2; ++mt)
#pragma unroll
        for (int r = 0; r < 4; ++r) { mrow[mt][r] = -3.0e38f; lrow[mt][r] = 0.f; }

    int sr = tid >> 2;          // staging row 0..63
    int scc = (tid & 3) * 8;    // staging col (bf16) 0..24

    for (int it = 0; it < 32; ++it) {
        int s0 = it * 128;
        f32x4 accS[2][8];
#pragma unroll
        for (int mt = 0; mt < 2; ++mt)
#pragma unroll
            for (int nt = 0; nt < 8; ++nt) accS[mt][nt] = (f32x4){0.f, 0.f, 0.f, 0.f};

        // ---- S = Q K^T over dh in 4 chunks of 32 ----
#pragma unroll
        for (int kc = 0; kc < 4; ++kc) {
            __syncthreads();
#pragma unroll
            for (int p = 0; p < 2; ++p) {
                int s = sr + p * 64;
                size_t go = (size_t)(s0 + s) * DH + kc * 32 + scc;
                *(float4*)&Ks[0][s][scc] = *(const float4*)&Kh[go];
                *(float4*)&Ks[1][s][scc] = *(const float4*)&Kl[go];
            }
            __syncthreads();
#pragma unroll
            for (int nt = 0; nt < 8; ++nt) {
                bf16x8 bh = *(const bf16x8*)&Ks[0][nt * 16 + lm][q * 8];
                bf16x8 bl = *(const bf16x8*)&Ks[1][nt * 16 + lm][q * 8];
#pragma unroll
                for (int mt = 0; mt < 2; ++mt) {
                    accS[mt][nt] = MFMA(qfh[mt][kc], bh, accS[mt][nt]);
                    accS[mt][nt] = MFMA(qfh[mt][kc], bl, accS[mt][nt]);
                    accS[mt][nt] = MFMA(qfl[mt][kc], bh, accS[mt][nt]);
                }
            }
        }

        // ---- bias + online softmax (rows live in 16-lane lm groups) ----
        float wv[8];
#pragma unroll
        for (int nt = 0; nt < 8; ++nt)
            wv[nt] = exp2f(-(float)((s0 + nt * 16 + lm) >> 1) * WEXP);
        bool iscos = (lm & 1);
        float rmax[2][4];
#pragma unroll
        for (int mt = 0; mt < 2; ++mt)
#pragma unroll
            for (int r = 0; r < 4; ++r) {
                float tf = (float)(m0 + wr0 + mt * 16 + q * 4 + r);
                float mx = -3.0e38f;
#pragma unroll
                for (int nt = 0; nt < 8; ++nt) {
                    float ang = tf * wv[nt];
                    float b = iscos ? __cosf(ang) : __sinf(ang);
                    float v = accS[mt][nt][r] + b;
                    accS[mt][nt][r] = v;
                    mx = fmaxf(mx, v);
                }
                rmax[mt][r] = mx;
            }
#pragma unroll
        for (int off = 1; off < 16; off <<= 1)
#pragma unroll
            for (int mt = 0; mt < 2; ++mt)
#pragma unroll
                for (int r = 0; r < 4; ++r)
                    rmax[mt][r] = fmaxf(rmax[mt][r], __shfl_xor(rmax[mt][r], off));
        float alpha[2][4], rsum[2][4];
#pragma unroll
        for (int mt = 0; mt < 2; ++mt)
#pragma unroll
            for (int r = 0; r < 4; ++r) {
                float mn = fmaxf(mrow[mt][r], rmax[mt][r]);
                alpha[mt][r] = exp2f((mrow[mt][r] - mn) * LOG2E);
                mrow[mt][r] = mn;
                rsum[mt][r] = 0.f;
            }
#pragma unroll
        for (int mt = 0; mt < 2; ++mt)
#pragma unroll
            for (int nt = 0; nt < 8; ++nt)
#pragma unroll
                for (int r = 0; r < 4; ++r) {
                    float p = exp2f((accS[mt][nt][r] - mrow[mt][r]) * LOG2E);
                    accS[mt][nt][r] = p;
                    rsum[mt][r] += p;
                }
#pragma unroll
        for (int off = 1; off < 16; off <<= 1)
#pragma unroll
            for (int mt = 0; mt < 2; ++mt)
#pragma unroll
                for (int r = 0; r < 4; ++r)
                    rsum[mt][r] += __shfl_xor(rsum[mt][r], off);
#pragma unroll
        for (int mt = 0; mt < 2; ++mt)
#pragma unroll
            for (int r = 0; r < 4; ++r)
                lrow[mt][r] = lrow[mt][r] * alpha[mt][r] + rsum[mt][r];
#pragma unroll
        for (int mt = 0; mt < 2; ++mt)
#pragma unroll
            for (int nt = 0; nt < 8; ++nt)
#pragma unroll
                for (int r = 0; r < 4; ++r)
                    accO[mt][nt][r] *= alpha[mt][r];

        // ---- P: D-layout regs -> LDS (safe: all waves passed K barriers) ----
#pragma unroll
        for (int mt = 0; mt < 2; ++mt)
#pragma unroll
            for (int nt = 0; nt < 8; ++nt)
#pragma unroll
                for (int r = 0; r < 4; ++r)
                    Ps[wr0 + mt * 16 + q * 4 + r][nt * 16 + lm] = (__bf16)accS[mt][nt][r];
        __syncthreads();

        // ---- O += P @ V  (V B-frags direct from global/L2, e-major Vt) ----
#pragma unroll
        for (int kc = 0; kc < 4; ++kc) {
            bf16x8 pa[2];
#pragma unroll
            for (int mt = 0; mt < 2; ++mt)
                pa[mt] = *(const bf16x8*)&Ps[wr0 + mt * 16 + lm][kc * 32 + q * 8];
#pragma unroll
            for (int nt = 0; nt < 8; ++nt) {
                bf16x8 vb = *(const bf16x8*)&Vh[(size_t)(nt * 16 + lm) * Tn + s0 + kc * 32 + q * 8];
#pragma unroll
                for (int mt = 0; mt < 2; ++mt)
                    accO[mt][nt] = MFMA(pa[mt], vb, accO[mt][nt]);
            }
        }
    }

    // ---- epilogue: O /= l, store into yh columns of this head ----
#pragma unroll
    for (int mt = 0; mt < 2; ++mt)
#pragma unroll
        for (int r = 0; r < 4; ++r) {
            float inv = 1.0f / lrow[mt][r];
            int t = m0 + wr0 + mt * 16 + q * 4 + r;
#pragma unroll
            for (int nt = 0; nt < 8; ++nt)
                yh[(size_t)t * Dm + h * DH + nt * 16 + lm] = accO[mt][nt][r] * inv;
        }
}

// ---------------------------------------------------------------------------
__global__ __launch_bounds__(256)
void reduce_kernel(const float* __restrict__ part, float* __restrict__ yh, int h) {
    int idx = blockIdx.x * 256 + threadIdx.x;
    int t = idx >> 7, e = idx & 127;
    float s = 0.f;
#pragma unroll
    for (int z = 0; z < 8; ++z) s += part[(size_t)z * Tn * DH + idx];
    yh[(size_t)t * Dm + h * DH + e] = s;
}

// ---------------------------------------------------------------------------
__global__ __launch_bounds__(256)
void softmax_kernel(float* __restrict__ S, __bf16* __restrict__ P, int writef32) {
    int t = blockIdx.x;
    float* row = S + (size_t)t * Tn;
    __bf16* prow = P + (size_t)t * Tn;
    int tid = threadIdx.x;
    float v[16];
    float m = -1e30f;
#pragma unroll
    for (int i = 0; i < 16; ++i) {
        v[i] = row[i * 256 + tid];
        m = fmaxf(m, v[i]);
    }
    __shared__ float redm[4];
    __shared__ float reds[4];
#pragma unroll
    for (int off = 32; off > 0; off >>= 1) m = fmaxf(m, __shfl_down(m, off));
    if ((tid & 63) == 0) redm[tid >> 6] = m;
    __syncthreads();
    m = fmaxf(fmaxf(redm[0], redm[1]), fmaxf(redm[2], redm[3]));
    float sum = 0.f;
#pragma unroll
    for (int i = 0; i < 16; ++i) {
        v[i] = __expf(v[i] - m);
        sum += v[i];
    }
#pragma unroll
    for (int off = 32; off > 0; off >>= 1) sum += __shfl_down(sum, off);
    if ((tid & 63) == 0) reds[tid >> 6] = sum;
    __syncthreads();
    sum = reds[0] + reds[1] + reds[2] + reds[3];
    float inv = 1.0f / sum;
#pragma unroll
    for (int i = 0; i < 16; ++i) {
        float rres = v[i] * inv;
        if (writef32) row[i * 256 + tid] = rres;
        prow[i * 256 + tid] = (__bf16)rres;
    }
}

// ---------------------------------------------------------------------------
extern "C" void kernel_launch(void* const* d_in, const int* in_sizes, int n_in,
                              void* d_out, int out_size, void* d_ws, size_t ws_size,
                              hipStream_t stream) {
    (void)in_sizes; (void)n_in; (void)out_size; (void)ws_size;
    const float* x    = (const float*)d_in[0];
    const float* Wq   = (const float*)d_in[1];
    const float* Wk   = (const float*)d_in[2];
    const float* Wv   = (const float*)d_in[3];
    const float* Wout = (const float*)d_in[4];

    float* out_y   = (float*)d_out;              // [4096][1024]
    float* out_att = out_y + (size_t)Tn * Dm;    // [4096][4096]

    const size_t MB = 1ull << 20;
    char* W = (char*)d_ws;
    __bf16* xhi  = (__bf16*)(W + 0 * MB);
    __bf16* xlo  = (__bf16*)(W + 8 * MB);
    __bf16* Wqhi = (__bf16*)(W + 16 * MB);
    __bf16* Wqlo = (__bf16*)(W + 18 * MB);
    __bf16* Wkhi = (__bf16*)(W + 20 * MB);
    __bf16* Wklo = (__bf16*)(W + 22 * MB);
    __bf16* Wvhi = (__bf16*)(W + 24 * MB);
    __bf16* Wvlo = (__bf16*)(W + 26 * MB);
    __bf16* Wohi = (__bf16*)(W + 28 * MB);
    __bf16* Wolo = (__bf16*)(W + 30 * MB);
    __bf16* Qhi  = (__bf16*)(W + 32 * MB);   // [H][T][DH]
    __bf16* Qlo  = (__bf16*)(W + 40 * MB);
    __bf16* Khi  = (__bf16*)(W + 48 * MB);
    __bf16* Klo  = (__bf16*)(W + 56 * MB);
    __bf16* Vb   = (__bf16*)(W + 64 * MB);   // [H][T][DH]
    __bf16* Vt   = (__bf16*)(W + 72 * MB);   // [H][DH][T]
    __bf16* Pb   = (__bf16*)(W + 80 * MB);   // [T][T] bf16 (head 7 only)
    float*  yh   = (float*)(W + 112 * MB);   // [T][1024]
    float*  part = (float*)(W + 128 * MB);   // [8][T][DH] (head 7)
    __bf16* yhhi = (__bf16*)(W + 128 * MB);  // dual-use after head loop
    __bf16* yhlo = (__bf16*)(W + 136 * MB);

    dim3 blk(256);

    split_kernel<<<dim3(Tn * Dm / 4 / 256), blk, 0, stream>>>(x, xhi, xlo, Tn * Dm / 4);
    split_kernel<<<dim3(Dm * Dm / 4 / 256), blk, 0, stream>>>(Wq, Wqhi, Wqlo, Dm * Dm / 4);
    split_kernel<<<dim3(Dm * Dm / 4 / 256), blk, 0, stream>>>(Wk, Wkhi, Wklo, Dm * Dm / 4);
    split_kernel<<<dim3(Dm * Dm / 4 / 256), blk, 0, stream>>>(Wv, Wvhi, Wvlo, Dm * Dm / 4);
    split_kernel<<<dim3(Dm * Dm / 4 / 256), blk, 0, stream>>>(Wout, Wohi, Wolo, Dm * Dm / 4);

    dim3 gp(Dm / 128, Tn / 128, 1);
    mfma_nt<<<gp, blk, 0, stream>>>(xhi, xlo, Wqhi, Wqlo, Dm, Dm, 0, Dm,
                                    nullptr, 0, 0, Qhi, Qlo, 1);
    mfma_nt<<<gp, blk, 0, stream>>>(xhi, xlo, Wkhi, Wklo, Dm, Dm, 0, Dm,
                                    nullptr, 0, 0, Khi, Klo, 1);
    mfma_nt<<<gp, blk, 0, stream>>>(xhi, xlo, Wvhi, Wvlo, Dm, Dm, 0, Dm,
                                    nullptr, 0, 0, Vb, nullptr, 2);
    vtrans_kernel<<<dim3(Tn / 64, DH / 64, Hn), blk, 0, stream>>>(Vb, Vt);

    // heads 0..6: fused flash attention (S never materialized)
    flash_kernel<<<dim3(Tn / 128, 7), blk, 0, stream>>>(Qhi, Qlo, Khi, Klo, Vt, yh);

    // head 7: unfused (fp32 att must be materialized as output att[-1])
    const size_t TD = (size_t)Tn * DH;
    {
        int h = 7;
        mfma_nt<<<dim3(Tn / 128, Tn / 128, 1), blk, 0, stream>>>(
            Qhi + h * TD, Qlo + h * TD, Khi + h * TD, Klo + h * TD,
            DH, DH, 0, DH, out_att, Tn, 0, nullptr, nullptr, 3);
        softmax_kernel<<<dim3(Tn), blk, 0, stream>>>(out_att, Pb, 1);
        mfma_nt<<<dim3(1, Tn / 128, 8), blk, 0, stream>>>(
            Pb, nullptr, Vt + h * TD, nullptr,
            Tn, Tn, 0, Tn / 8, part, 0, 0, nullptr, nullptr, 5);
        reduce_kernel<<<dim3(Tn * DH / 256), blk, 0, stream>>>(part, yh, h);
    }

    split_kernel<<<dim3(Tn * Dm / 4 / 256), blk, 0, stream>>>(yh, yhhi, yhlo, Tn * Dm / 4);
    mfma_nt<<<gp, blk, 0, stream>>>(yhhi, yhlo, Wohi, Wolo, Dm, Dm, 0, Dm,
                                    out_y, Dm, 0, nullptr, nullptr, 0);
}

// Round 5
// 906.165 us; speedup vs baseline: 3.2483x; 1.2238x over previous
//
#include <hip/hip_runtime.h>
#include <math.h>

#define Tn 4096
#define Dm 1024
#define Hn 8
#define DH 128

typedef __bf16 bf16x8 __attribute__((ext_vector_type(8)));
typedef float f32x4 __attribute__((ext_vector_type(4)));

#define LDS_STRIDE 40   // 32 + 8 pad (bf16 units)
#define LOG2E 1.4426950408889634f
#define WEXP 0.025952563241307518f  // log2(10000)/512

#define MFMA(a, b, c) __builtin_amdgcn_mfma_f32_16x16x32_bf16((a), (b), (c), 0, 0, 0)

// ---------------------------------------------------------------------------
// fp32 -> (hi, lo) bf16 split
__global__ __launch_bounds__(256)
void split_kernel(const float* __restrict__ in, __bf16* __restrict__ hi,
                  __bf16* __restrict__ lo, int n4) {
    int idx = blockIdx.x * 256 + threadIdx.x;
    if (idx >= n4) return;
    float4 v = ((const float4*)in)[idx];
    __attribute__((aligned(8))) __bf16 h[4], l[4];
    h[0] = (__bf16)v.x; h[1] = (__bf16)v.y; h[2] = (__bf16)v.z; h[3] = (__bf16)v.w;
    l[0] = (__bf16)(v.x - (float)h[0]);
    l[1] = (__bf16)(v.y - (float)h[1]);
    l[2] = (__bf16)(v.z - (float)h[2]);
    l[3] = (__bf16)(v.w - (float)h[3]);
    *(float2*)&hi[(size_t)idx * 4] = *(float2*)h;
    *(float2*)&lo[(size_t)idx * 4] = *(float2*)l;
}

// V[h][t][e] bf16 -> Vt[h][e][t] bf16
__global__ __launch_bounds__(256)
void vtrans_kernel(const __bf16* __restrict__ V, __bf16* __restrict__ Vt) {
    __shared__ __bf16 tile[64][80];
    int h = blockIdx.z, t0 = blockIdx.x * 64, e0 = blockIdx.y * 64;
    const __bf16* Vh = V + (size_t)h * Tn * DH;
    __bf16* Vth = Vt + (size_t)h * DH * Tn;
#pragma unroll
    for (int p = 0; p < 2; ++p) {
        int r = (threadIdx.x >> 3) + p * 32;
        int c = (threadIdx.x & 7) * 8;
        *(float4*)&tile[r][c] = *(const float4*)&Vh[(size_t)(t0 + r) * DH + e0 + c];
    }
    __syncthreads();
#pragma unroll
    for (int p = 0; p < 2; ++p) {
        int r = (threadIdx.x >> 3) + p * 32;
        int c = (threadIdx.x & 7) * 8;
        __attribute__((aligned(16))) __bf16 tmp[8];
#pragma unroll
        for (int j = 0; j < 8; ++j) tmp[j] = tile[c + j][r];
        *(float4*)&Vth[(size_t)(e0 + r) * Tn + t0 + c] = *(float4*)tmp;
    }
}

// ---------------------------------------------------------------------------
// Shared 128x128-tile NT GEMM body (BK=32, 4 waves 2x2, optional hi/lo 3-pass)
// ---------------------------------------------------------------------------
__device__ __forceinline__
void gemm_body(__bf16 (*smem)[128 * LDS_STRIDE],
               const __bf16* __restrict__ Ahi, const __bf16* __restrict__ Alo,
               const __bf16* __restrict__ Bhi, const __bf16* __restrict__ Blo,
               int ldA, int ldB, int K, int m0, int n0, f32x4 acc[4][4]) {
    int tid = threadIdx.x;
    int lane = tid & 63, wid = tid >> 6;
    int wm = (wid >> 1) * 64, wn = (wid & 1) * 64;
    int lm = lane & 15, q = lane >> 4;
    int sr = tid >> 2;
    int sc = (tid & 3) * 8;
    const bool split = (Alo != nullptr);
    for (int k0 = 0; k0 < K; k0 += 32) {
        __syncthreads();
#pragma unroll
        for (int p = 0; p < 128; p += 64) {
            int r = sr + p;
            *(float4*)&smem[0][r * LDS_STRIDE + sc] =
                *(const float4*)&Ahi[(size_t)(m0 + r) * ldA + k0 + sc];
            *(float4*)&smem[2][r * LDS_STRIDE + sc] =
                *(const float4*)&Bhi[(size_t)(n0 + r) * ldB + k0 + sc];
            if (split) {
                *(float4*)&smem[1][r * LDS_STRIDE + sc] =
                    *(const float4*)&Alo[(size_t)(m0 + r) * ldA + k0 + sc];
                *(float4*)&smem[3][r * LDS_STRIDE + sc] =
                    *(const float4*)&Blo[(size_t)(n0 + r) * ldB + k0 + sc];
            }
        }
        __syncthreads();
        bf16x8 ah[4], bh[4], al[4], bl[4];
#pragma unroll
        for (int mt = 0; mt < 4; ++mt) {
            ah[mt] = *(const bf16x8*)&smem[0][(wm + mt * 16 + lm) * LDS_STRIDE + q * 8];
            if (split)
                al[mt] = *(const bf16x8*)&smem[1][(wm + mt * 16 + lm) * LDS_STRIDE + q * 8];
        }
#pragma unroll
        for (int nt = 0; nt < 4; ++nt) {
            bh[nt] = *(const bf16x8*)&smem[2][(wn + nt * 16 + lm) * LDS_STRIDE + q * 8];
            if (split)
                bl[nt] = *(const bf16x8*)&smem[3][(wn + nt * 16 + lm) * LDS_STRIDE + q * 8];
        }
#pragma unroll
        for (int mt = 0; mt < 4; ++mt)
#pragma unroll
            for (int nt = 0; nt < 4; ++nt) {
                acc[mt][nt] = MFMA(ah[mt], bh[nt], acc[mt][nt]);
                if (split) {
                    acc[mt][nt] = MFMA(ah[mt], bl[nt], acc[mt][nt]);
                    acc[mt][nt] = MFMA(al[mt], bh[nt], acc[mt][nt]);
                }
            }
    }
}

// ---------------------------------------------------------------------------
// Fused QKV projection: blockIdx.z selects Q/K/V. Output in [h][t][e] layout,
// Q/K split hi/lo, V plain bf16.
// ---------------------------------------------------------------------------
__global__ __launch_bounds__(256)
void qkv_kernel(const __bf16* __restrict__ xhi, const __bf16* __restrict__ xlo,
                const __bf16* __restrict__ Wqh, const __bf16* __restrict__ Wql,
                const __bf16* __restrict__ Wkh, const __bf16* __restrict__ Wkl,
                const __bf16* __restrict__ Wvh, const __bf16* __restrict__ Wvl,
                __bf16* __restrict__ Qh, __bf16* __restrict__ Ql,
                __bf16* __restrict__ Kh, __bf16* __restrict__ Kl,
                __bf16* __restrict__ Vb) {
    __shared__ __bf16 smem[4][128 * LDS_STRIDE];
    int z = blockIdx.z;
    const __bf16* Bh = (z == 0) ? Wqh : (z == 1) ? Wkh : Wvh;
    const __bf16* Bl = (z == 0) ? Wql : (z == 1) ? Wkl : Wvl;
    __bf16* Oh = (z == 0) ? Qh : (z == 1) ? Kh : Vb;
    __bf16* Ol = (z == 0) ? Ql : (z == 1) ? Kl : nullptr;
    int m0 = blockIdx.y * 128, n0 = blockIdx.x * 128;
    int tid = threadIdx.x, lane = tid & 63, wid = tid >> 6;
    int wm = (wid >> 1) * 64, wn = (wid & 1) * 64;
    int lm = lane & 15, q = lane >> 4;
    f32x4 acc[4][4];
#pragma unroll
    for (int i = 0; i < 4; ++i)
#pragma unroll
        for (int j = 0; j < 4; ++j) acc[i][j] = (f32x4){0.f, 0.f, 0.f, 0.f};
    gemm_body(smem, xhi, xlo, Bh, Bl, Dm, Dm, Dm, m0, n0, acc);
#pragma unroll
    for (int mt = 0; mt < 4; ++mt)
#pragma unroll
        for (int r = 0; r < 4; ++r) {
            int grow = m0 + wm + mt * 16 + q * 4 + r;
#pragma unroll
            for (int nt = 0; nt < 4; ++nt) {
                int gc = n0 + wn + nt * 16 + lm;
                int h = gc >> 7, e = gc & 127;
                size_t o = ((size_t)h * Tn + grow) * DH + e;
                float v = acc[mt][nt][r];
                __bf16 hv = (__bf16)v;
                Oh[o] = hv;
                if (Ol) Ol[o] = (__bf16)(v - (float)hv);
            }
        }
}

// ---------------------------------------------------------------------------
// Output projection: C = A B^T fp32 store
// ---------------------------------------------------------------------------
__global__ __launch_bounds__(256)
void gemm_out(const __bf16* __restrict__ Ahi, const __bf16* __restrict__ Alo,
              const __bf16* __restrict__ Bhi, const __bf16* __restrict__ Blo,
              float* __restrict__ C) {
    __shared__ __bf16 smem[4][128 * LDS_STRIDE];
    int m0 = blockIdx.y * 128, n0 = blockIdx.x * 128;
    int tid = threadIdx.x, lane = tid & 63, wid = tid >> 6;
    int wm = (wid >> 1) * 64, wn = (wid & 1) * 64;
    int lm = lane & 15, q = lane >> 4;
    f32x4 acc[4][4];
#pragma unroll
    for (int i = 0; i < 4; ++i)
#pragma unroll
        for (int j = 0; j < 4; ++j) acc[i][j] = (f32x4){0.f, 0.f, 0.f, 0.f};
    gemm_body(smem, Ahi, Alo, Bhi, Blo, Dm, Dm, Dm, m0, n0, acc);
#pragma unroll
    for (int mt = 0; mt < 4; ++mt)
#pragma unroll
        for (int r = 0; r < 4; ++r) {
            int grow = m0 + wm + mt * 16 + q * 4 + r;
#pragma unroll
            for (int nt = 0; nt < 4; ++nt)
                C[(size_t)grow * Dm + n0 + wn + nt * 16 + lm] = acc[mt][nt][r];
        }
}

// ---------------------------------------------------------------------------
// Flash attention, all 8 heads. 1-D grid of 512 blocks: head = bid&7 (XCD
// round-robin pins each head's K/V to one XCD L2), qtile = bid>>3 (64 rows).
// 4 waves x 16 Q-rows. Head 7 exports final m,l per row for att regeneration.
// ---------------------------------------------------------------------------
__global__ __launch_bounds__(256, 2)
void flash_kernel(const __bf16* __restrict__ Qhi, const __bf16* __restrict__ Qlo,
                  const __bf16* __restrict__ Khi, const __bf16* __restrict__ Klo,
                  const __bf16* __restrict__ Vt, float* __restrict__ yh,
                  float* __restrict__ mM, float* __restrict__ lL) {
    __shared__ __bf16 Ks[2][128][40];   // 20480 B
    __shared__ __bf16 Ps[64][132];      // 16896 B
    int bid = blockIdx.x;
    int h = bid & 7;
    int m0 = (bid >> 3) * 64;
    const size_t TD = (size_t)Tn * DH;
    const __bf16* Qh = Qhi + h * TD;
    const __bf16* Ql = Qlo + h * TD;
    const __bf16* Kh = Khi + h * TD;
    const __bf16* Kl = Klo + h * TD;
    const __bf16* Vh = Vt + h * TD;

    int tid = threadIdx.x;
    int lane = tid & 63, wid = tid >> 6;
    int lm = lane & 15, q = lane >> 4;
    int wr0 = wid * 16;

    bf16x8 qfh[4], qfl[4];
#pragma unroll
    for (int kc = 0; kc < 4; ++kc) {
        size_t o = (size_t)(m0 + wr0 + lm) * DH + kc * 32 + q * 8;
        qfh[kc] = *(const bf16x8*)&Qh[o];
        qfl[kc] = *(const bf16x8*)&Ql[o];
    }

    f32x4 accO[8];
#pragma unroll
    for (int nt = 0; nt < 8; ++nt) accO[nt] = (f32x4){0.f, 0.f, 0.f, 0.f};
    float mrow[4], lrow[4];
#pragma unroll
    for (int r = 0; r < 4; ++r) { mrow[r] = -3.0e38f; lrow[r] = 0.f; }

    int sr = tid >> 2;
    int scc = (tid & 3) * 8;
    bool iscos = (lm & 1);

    for (int it = 0; it < 32; ++it) {
        int s0 = it * 128;
        f32x4 accS[8];
#pragma unroll
        for (int nt = 0; nt < 8; ++nt) accS[nt] = (f32x4){0.f, 0.f, 0.f, 0.f};

        // ---- S = Q K^T (3-pass split) ----
#pragma unroll
        for (int kc = 0; kc < 4; ++kc) {
            __syncthreads();
#pragma unroll
            for (int p = 0; p < 2; ++p) {
                int s = sr + p * 64;
                size_t go = (size_t)(s0 + s) * DH + kc * 32 + scc;
                *(float4*)&Ks[0][s][scc] = *(const float4*)&Kh[go];
                *(float4*)&Ks[1][s][scc] = *(const float4*)&Kl[go];
            }
            __syncthreads();
#pragma unroll
            for (int nt = 0; nt < 8; ++nt) {
                bf16x8 bh = *(const bf16x8*)&Ks[0][nt * 16 + lm][q * 8];
                bf16x8 bl = *(const bf16x8*)&Ks[1][nt * 16 + lm][q * 8];
                accS[nt] = MFMA(qfh[kc], bh, accS[nt]);
                accS[nt] = MFMA(qfh[kc], bl, accS[nt]);
                accS[nt] = MFMA(qfl[kc], bh, accS[nt]);
            }
        }

        // ---- bias + online softmax (row state in 16-lane lm groups) ----
        float wv[8];
#pragma unroll
        for (int nt = 0; nt < 8; ++nt)
            wv[nt] = exp2f(-(float)((s0 + nt * 16 + lm) >> 1) * WEXP);
        float rmax[4];
#pragma unroll
        for (int r = 0; r < 4; ++r) {
            float tf = (float)(m0 + wr0 + q * 4 + r);
            float mx = -3.0e38f;
#pragma unroll
            for (int nt = 0; nt < 8; ++nt) {
                float ang = tf * wv[nt];
                float b = iscos ? __cosf(ang) : __sinf(ang);
                float v = accS[nt][r] + b;
                accS[nt][r] = v;
                mx = fmaxf(mx, v);
            }
            rmax[r] = mx;
        }
#pragma unroll
        for (int off = 1; off < 16; off <<= 1)
#pragma unroll
            for (int r = 0; r < 4; ++r)
                rmax[r] = fmaxf(rmax[r], __shfl_xor(rmax[r], off));
        float alpha[4], rsum[4];
#pragma unroll
        for (int r = 0; r < 4; ++r) {
            float mn = fmaxf(mrow[r], rmax[r]);
            alpha[r] = exp2f((mrow[r] - mn) * LOG2E);
            mrow[r] = mn;
            rsum[r] = 0.f;
        }
#pragma unroll
        for (int nt = 0; nt < 8; ++nt)
#pragma unroll
            for (int r = 0; r < 4; ++r) {
                float p = exp2f((accS[nt][r] - mrow[r]) * LOG2E);
                accS[nt][r] = p;
                rsum[r] += p;
            }
#pragma unroll
        for (int off = 1; off < 16; off <<= 1)
#pragma unroll
            for (int r = 0; r < 4; ++r)
                rsum[r] += __shfl_xor(rsum[r], off);
#pragma unroll
        for (int r = 0; r < 4; ++r)
            lrow[r] = lrow[r] * alpha[r] + rsum[r];
#pragma unroll
        for (int nt = 0; nt < 8; ++nt)
#pragma unroll
            for (int r = 0; r < 4; ++r)
                accO[nt][r] *= alpha[r];

        // ---- P relayout via LDS ----
#pragma unroll
        for (int nt = 0; nt < 8; ++nt)
#pragma unroll
            for (int r = 0; r < 4; ++r)
                Ps[wr0 + q * 4 + r][nt * 16 + lm] = (__bf16)accS[nt][r];
        __syncthreads();

        // ---- O += P @ V (V B-frags direct from L2) ----
#pragma unroll
        for (int kc = 0; kc < 4; ++kc) {
            bf16x8 pa = *(const bf16x8*)&Ps[wr0 + lm][kc * 32 + q * 8];
#pragma unroll
            for (int nt = 0; nt < 8; ++nt) {
                bf16x8 vb = *(const bf16x8*)&Vh[(size_t)(nt * 16 + lm) * Tn + s0 + kc * 32 + q * 8];
                accO[nt] = MFMA(pa, vb, accO[nt]);
            }
        }
    }

    // ---- epilogue ----
#pragma unroll
    for (int r = 0; r < 4; ++r) {
        float inv = 1.0f / lrow[r];
        int t = m0 + wr0 + q * 4 + r;
#pragma unroll
        for (int nt = 0; nt < 8; ++nt)
            yh[(size_t)t * Dm + h * DH + nt * 16 + lm] = accO[nt][r] * inv;
    }
    if (h == 7 && lm == 0) {
#pragma unroll
        for (int r = 0; r < 4; ++r) {
            int t = m0 + wr0 + q * 4 + r;
            mM[t] = mrow[r];
            lL[t] = lrow[r];
        }
    }
}

// ---------------------------------------------------------------------------
// att[-1] regeneration: S7 = Q7 K7^T (3-pass) + bias, att = exp2((S-m)lg2e)/l,
// stored via LDS-staged coalesced epilogue (two 64-col phases).
// ---------------------------------------------------------------------------
__global__ __launch_bounds__(256)
void att_kernel(const __bf16* __restrict__ Ahi, const __bf16* __restrict__ Alo,
                const __bf16* __restrict__ Bhi, const __bf16* __restrict__ Blo,
                const float* __restrict__ mM, const float* __restrict__ lL,
                float* __restrict__ att) {
    __shared__ __align__(16) char shraw[4 * 128 * LDS_STRIDE * 2];  // 40960 B
    __bf16 (*smem)[128 * LDS_STRIDE] = reinterpret_cast<__bf16(*)[128 * LDS_STRIDE]>(shraw);
    float (*Ls)[68] = reinterpret_cast<float(*)[68]>(shraw);        // 34816 B

    int m0 = blockIdx.y * 128, n0 = blockIdx.x * 128;
    int tid = threadIdx.x, lane = tid & 63, wid = tid >> 6;
    int wm = (wid >> 1) * 64, wn = (wid & 1) * 64;
    int lm = lane & 15, q = lane >> 4;
    f32x4 acc[4][4];
#pragma unroll
    for (int i = 0; i < 4; ++i)
#pragma unroll
        for (int j = 0; j < 4; ++j) acc[i][j] = (f32x4){0.f, 0.f, 0.f, 0.f};
    gemm_body(smem, Ahi, Alo, Bhi, Blo, DH, DH, DH, m0, n0, acc);

    // normalize in-register
    float wv[4];
#pragma unroll
    for (int nt = 0; nt < 4; ++nt) {
        int s = n0 + wn + nt * 16 + lm;
        wv[nt] = exp2f(-(float)(s >> 1) * WEXP);
    }
    int par = lm & 1;
#pragma unroll
    for (int mt = 0; mt < 4; ++mt)
#pragma unroll
        for (int r = 0; r < 4; ++r) {
            int t = m0 + wm + mt * 16 + q * 4 + r;
            float tf = (float)t;
            float mr = mM[t];
            float linv = 1.0f / lL[t];
#pragma unroll
            for (int nt = 0; nt < 4; ++nt) {
                float sv, cv;
                sincosf(tf * wv[nt], &sv, &cv);
                float bias = par ? cv : sv;
                acc[mt][nt][r] = exp2f((acc[mt][nt][r] + bias - mr) * LOG2E) * linv;
            }
        }

    // two-phase LDS-staged coalesced store (cols wn = p*64)
#pragma unroll
    for (int p = 0; p < 2; ++p) {
        __syncthreads();
        if ((wid & 1) == p) {
#pragma unroll
            for (int mt = 0; mt < 4; ++mt)
#pragma unroll
                for (int r = 0; r < 4; ++r)
#pragma unroll
                    for (int nt = 0; nt < 4; ++nt)
                        Ls[wm + mt * 16 + q * 4 + r][nt * 16 + lm] = acc[mt][nt][r];
        }
        __syncthreads();
#pragma unroll
        for (int j = 0; j < 8; ++j) {
            int row = j * 16 + (tid >> 4);
            int col = (tid & 15) * 4;
            float4 v = *(float4*)&Ls[row][col];
            *(float4*)&att[(size_t)(m0 + row) * Tn + n0 + p * 64 + col] = v;
        }
    }
}

// ---------------------------------------------------------------------------
extern "C" void kernel_launch(void* const* d_in, const int* in_sizes, int n_in,
                              void* d_out, int out_size, void* d_ws, size_t ws_size,
                              hipStream_t stream) {
    (void)in_sizes; (void)n_in; (void)out_size; (void)ws_size;
    const float* x    = (const float*)d_in[0];
    const float* Wq   = (const float*)d_in[1];
    const float* Wk   = (const float*)d_in[2];
    const float* Wv   = (const float*)d_in[3];
    const float* Wout = (const float*)d_in[4];

    float* out_y   = (float*)d_out;              // [4096][1024]
    float* out_att = out_y + (size_t)Tn * Dm;    // [4096][4096]

    const size_t MB = 1ull << 20;
    char* W = (char*)d_ws;
    __bf16* xhi  = (__bf16*)(W + 0 * MB);
    __bf16* xlo  = (__bf16*)(W + 8 * MB);
    __bf16* Wqhi = (__bf16*)(W + 16 * MB);
    __bf16* Wqlo = (__bf16*)(W + 18 * MB);
    __bf16* Wkhi = (__bf16*)(W + 20 * MB);
    __bf16* Wklo = (__bf16*)(W + 22 * MB);
    __bf16* Wvhi = (__bf16*)(W + 24 * MB);
    __bf16* Wvlo = (__bf16*)(W + 26 * MB);
    __bf16* Wohi = (__bf16*)(W + 28 * MB);
    __bf16* Wolo = (__bf16*)(W + 30 * MB);
    __bf16* Qhi  = (__bf16*)(W + 32 * MB);   // [H][T][DH]
    __bf16* Qlo  = (__bf16*)(W + 40 * MB);
    __bf16* Khi  = (__bf16*)(W + 48 * MB);
    __bf16* Klo  = (__bf16*)(W + 56 * MB);
    __bf16* Vb   = (__bf16*)(W + 64 * MB);   // [H][T][DH]
    __bf16* Vt   = (__bf16*)(W + 72 * MB);   // [H][DH][T]
    float*  mM   = (float*)(W + 80 * MB);    // [T]
    float*  lL   = (float*)(W + 81 * MB);    // [T]
    float*  yh   = (float*)(W + 112 * MB);   // [T][1024]
    __bf16* yhhi = (__bf16*)(W + 128 * MB);
    __bf16* yhlo = (__bf16*)(W + 136 * MB);

    dim3 blk(256);

    split_kernel<<<dim3(Tn * Dm / 4 / 256), blk, 0, stream>>>(x, xhi, xlo, Tn * Dm / 4);
    split_kernel<<<dim3(Dm * Dm / 4 / 256), blk, 0, stream>>>(Wq, Wqhi, Wqlo, Dm * Dm / 4);
    split_kernel<<<dim3(Dm * Dm / 4 / 256), blk, 0, stream>>>(Wk, Wkhi, Wklo, Dm * Dm / 4);
    split_kernel<<<dim3(Dm * Dm / 4 / 256), blk, 0, stream>>>(Wv, Wvhi, Wvlo, Dm * Dm / 4);
    split_kernel<<<dim3(Dm * Dm / 4 / 256), blk, 0, stream>>>(Wout, Wohi, Wolo, Dm * Dm / 4);

    // fused QKV projection (z: 0=Q split, 1=K split, 2=V plain)
    qkv_kernel<<<dim3(Dm / 128, Tn / 128, 3), blk, 0, stream>>>(
        xhi, xlo, Wqhi, Wqlo, Wkhi, Wklo, Wvhi, Wvlo,
        Qhi, Qlo, Khi, Klo, Vb);
    vtrans_kernel<<<dim3(Tn / 64, DH / 64, Hn), blk, 0, stream>>>(Vb, Vt);

    // flash attention, all 8 heads (head = bid&7 for XCD L2 locality)
    flash_kernel<<<dim3(512), blk, 0, stream>>>(Qhi, Qlo, Khi, Klo, Vt, yh, mM, lL);

    // att[-1] regeneration from head-7 m,l
    const size_t TD = (size_t)Tn * DH;
    att_kernel<<<dim3(Tn / 128, Tn / 128), blk, 0, stream>>>(
        Qhi + 7 * TD, Qlo + 7 * TD, Khi + 7 * TD, Klo + 7 * TD, mM, lL, out_att);

    // output projection
    split_kernel<<<dim3(Tn * Dm / 4 / 256), blk, 0, stream>>>(yh, yhhi, yhlo, Tn * Dm / 4);
    gemm_out<<<dim3(Dm / 128, Tn / 128), blk, 0, stream>>>(yhhi, yhlo, Wohi, Wolo, out_y);
}